// Round 1
// baseline (246.050 us; speedup 1.0000x reference)
//
#include <hip/hip_runtime.h>
#include <cstdint>

// ---------------------------------------------------------------------------
// CTC loss pipeline: bf16 MFMA GEMM -> log_softmax+gather(exp) -> linear-domain
// scaled CTC forward -> mean reduce.
// ---------------------------------------------------------------------------

#define SPAD 260                      // padded extended-state row (257 -> 260, 16B-aligned rows)
#define L2E 1.4426950408889634f
#define LN2 0.6931471805599453f

typedef short v8s __attribute__((ext_vector_type(8)));
typedef float v4f __attribute__((ext_vector_type(4)));

__device__ __forceinline__ uint32_t f2bf_bits(float f) {
  uint32_t u = __float_as_uint(f);
  return (u + 0x7FFFu + ((u >> 16) & 1u)) >> 16;   // RNE
}
__device__ __forceinline__ float bf2f(uint32_t h) { return __uint_as_float(h << 16); }

// ---------------- k0a: x fp32 -> bf16 ----------------
__global__ void k_convert_x(const float* __restrict__ x, uint16_t* __restrict__ xb, long long n) {
  long long i = ((long long)blockIdx.x * blockDim.x + threadIdx.x) * 8;
  if (i >= n) return;
  float4 a = *(const float4*)(x + i);
  float4 b = *(const float4*)(x + i + 4);
  uint4 o;
  o.x = f2bf_bits(a.x) | (f2bf_bits(a.y) << 16);
  o.y = f2bf_bits(a.z) | (f2bf_bits(a.w) << 16);
  o.z = f2bf_bits(b.x) | (f2bf_bits(b.y) << 16);
  o.w = f2bf_bits(b.z) | (f2bf_bits(b.w) << 16);
  *(uint4*)(xb + i) = o;
}

// ---------------- k0b: W[D,V] fp32 -> Wt[V,D] bf16 (transpose via LDS) ----------------
__global__ void k_transpose_w(const float* __restrict__ W, uint16_t* __restrict__ Wt, int D, int V) {
  __shared__ float tile[32][33];
  int n0 = blockIdx.x * 32, k0 = blockIdx.y * 32;
  int tx = threadIdx.x, ty = threadIdx.y;   // block (32,8)
  #pragma unroll
  for (int i = 0; i < 32; i += 8)
    tile[ty + i][tx] = W[(size_t)(k0 + ty + i) * V + n0 + tx];
  __syncthreads();
  #pragma unroll
  for (int i = 0; i < 32; i += 8)
    Wt[(size_t)(n0 + ty + i) * D + k0 + tx] = (uint16_t)f2bf_bits(tile[tx][ty + i]);
}

// ---------------- k1: bf16 GEMM (m97 structure), C = A*Wt^T + bias ----------------
// A: [M,K] bf16 row-major, Bt: [N,K] bf16 row-major (= W^T), C: [M,N] (fp32 or bf16)
template <typename CT>
__global__ __launch_bounds__(256) void k_gemm(const uint16_t* __restrict__ A,
                                              const uint16_t* __restrict__ Bt,
                                              const float* __restrict__ bias,
                                              CT* __restrict__ C, int M, int N, int K) {
  __shared__ uint16_t As[128 * 32];   // 8 KB, row r at ushort r*32 (64B rows, packed for global_load_lds)
  __shared__ uint16_t Bs[128 * 32];
  const int tid = threadIdx.x, lane = tid & 63, wave = tid >> 6;
  const int m0 = blockIdx.x * 128, n0 = blockIdx.y * 128;
  const int wm = wave & 1, wn = wave >> 1;      // wave -> 64x64 subtile
  const int frow = lane & 15, kb = lane >> 4;   // MFMA A/B operand lane mapping
  const int lr = lane >> 2, kc = lane & 3;      // staging: lane -> (row-within-16, 16B chunk)
  v4f acc[4][4] = {};

  for (int k0 = 0; k0 < K; k0 += 32) {
    __syncthreads();   // protect LDS from previous iteration's readers
    #pragma unroll
    for (int i = 0; i < 2; i++) {
      const int r = (wave * 2 + i) * 16 + lr;   // tile row 0..127
      const uint16_t* ga = A + (size_t)(m0 + r) * K + k0 + kc * 8;
      const uint16_t* gb = Bt + (size_t)(n0 + r) * K + k0 + kc * 8;
      __builtin_amdgcn_global_load_lds(
          (const __attribute__((address_space(1))) void*)ga,
          (__attribute__((address_space(3))) void*)(As + (wave * 2 + i) * 512 + lane * 8), 16, 0, 0);
      __builtin_amdgcn_global_load_lds(
          (const __attribute__((address_space(1))) void*)gb,
          (__attribute__((address_space(3))) void*)(Bs + (wave * 2 + i) * 512 + lane * 8), 16, 0, 0);
    }
    __syncthreads();   // compiler drains vmcnt before s_barrier -> LDS is valid

    v8s af[4], bf[4];
    #pragma unroll
    for (int i = 0; i < 4; i++)
      af[i] = *(const v8s*)(As + (wm * 64 + i * 16 + frow) * 32 + kb * 8);
    #pragma unroll
    for (int j = 0; j < 4; j++)
      bf[j] = *(const v8s*)(Bs + (wn * 64 + j * 16 + frow) * 32 + kb * 8);
    #pragma unroll
    for (int i = 0; i < 4; i++)
      #pragma unroll
      for (int j = 0; j < 4; j++)
        acc[i][j] = __builtin_amdgcn_mfma_f32_16x16x32_bf16(af[i], bf[j], acc[i][j], 0, 0, 0);
  }

  // epilogue: C/D layout col=lane&15, row=(lane>>4)*4+reg  [m89-verified]
  const int crow = (lane >> 4) * 4, ccol = lane & 15;
  #pragma unroll
  for (int j = 0; j < 4; j++) {
    const int n = n0 + wn * 64 + j * 16 + ccol;
    const float bv = bias[n];
    #pragma unroll
    for (int i = 0; i < 4; i++) {
      const int mb = m0 + wm * 64 + i * 16 + crow;
      #pragma unroll
      for (int r2 = 0; r2 < 4; r2++) {
        float v = acc[i][j][r2] + bv;
        if constexpr (sizeof(CT) == 2) C[(size_t)(mb + r2) * N + n] = (CT)f2bf_bits(v);
        else                           C[(size_t)(mb + r2) * N + n] = v;
      }
    }
  }
}

// ---------------- k2: per-row logsumexp + gather ext-label probs (linear domain) ----------------
// p_ext[row][s] = exp(logit[label(s)] - lse)  for s < S=2*Lb+1, else 0. Row stride SPAD.
template <typename CT>
__global__ void k_softmax_gather(const CT* __restrict__ logits, const int* __restrict__ target,
                                 const int* __restrict__ tlen, float* __restrict__ pext,
                                 int T, int V, int L) {
  const int row = blockIdx.x * 4 + (threadIdx.x >> 6);   // one wave per row
  const int lane = threadIdx.x & 63;
  const CT* lrow = logits + (size_t)row * V;

  float xs[16];
  int cnt = 0;
  float mx = -INFINITY;
  for (int base = 0; base < V; base += 256) {
    const int idx = base + lane * 4;
    float4 v;
    if constexpr (sizeof(CT) == 2) {
      uint2 u = *(const uint2*)((const uint16_t*)lrow + idx);
      v.x = bf2f(u.x & 0xFFFFu); v.y = bf2f(u.x >> 16);
      v.z = bf2f(u.y & 0xFFFFu); v.w = bf2f(u.y >> 16);
    } else {
      v = *(const float4*)((const float*)lrow + idx);
    }
    xs[cnt] = v.x; xs[cnt + 1] = v.y; xs[cnt + 2] = v.z; xs[cnt + 3] = v.w; cnt += 4;
    mx = fmaxf(mx, fmaxf(fmaxf(v.x, v.y), fmaxf(v.z, v.w)));
  }
  #pragma unroll
  for (int off = 32; off; off >>= 1) mx = fmaxf(mx, __shfl_xor(mx, off, 64));
  float sum = 0.f;
  #pragma unroll
  for (int q = 0; q < 16; q++) { if (q < cnt) sum += exp2f((xs[q] - mx) * L2E); }
  #pragma unroll
  for (int off = 32; off; off >>= 1) sum += __shfl_xor(sum, off, 64);
  const float lse2 = mx * L2E + log2f(sum);   // lse in log2 units

  const int bidx = row / T;
  const int Lb = tlen[bidx];
  const int S = 2 * Lb + 1;
  float* prow = pext + (size_t)row * SPAD;
  for (int s = lane; s < SPAD; s += 64) {
    float p = 0.f;
    if (s < S) {
      const int lbl = (s & 1) ? target[bidx * L + ((s - 1) >> 1)] : 0;   // blank=0
      float lg;
      if constexpr (sizeof(CT) == 2) lg = bf2f(((const uint16_t*)lrow)[lbl]);
      else                           lg = ((const float*)lrow)[lbl];
      p = exp2f(lg * L2E - lse2);
    }
    prow[s] = p;
  }
}

// ---------------- k3: scaled linear-domain CTC forward, 1 wave per batch ----------------
__device__ __forceinline__ float wave_shr1(float x) {   // lane l <- lane l-1, lane0 <- 0
  return __int_as_float(__builtin_amdgcn_update_dpp(0, __float_as_int(x), 0x138, 0xf, 0xf, true));
}
__device__ __forceinline__ float wave_max_nonneg(float x) {   // all values >= 0
  x = fmaxf(x, __int_as_float(__builtin_amdgcn_update_dpp(0, __float_as_int(x), 0x111, 0xf, 0xf, true)));
  x = fmaxf(x, __int_as_float(__builtin_amdgcn_update_dpp(0, __float_as_int(x), 0x112, 0xf, 0xf, true)));
  x = fmaxf(x, __int_as_float(__builtin_amdgcn_update_dpp(0, __float_as_int(x), 0x114, 0xf, 0xf, true)));
  x = fmaxf(x, __int_as_float(__builtin_amdgcn_update_dpp(0, __float_as_int(x), 0x118, 0xf, 0xf, true)));
  x = fmaxf(x, __int_as_float(__builtin_amdgcn_update_dpp(0, __float_as_int(x), 0x142, 0xf, 0xf, true)));
  x = fmaxf(x, __int_as_float(__builtin_amdgcn_update_dpp(0, __float_as_int(x), 0x143, 0xf, 0xf, true)));
  return __int_as_float(__builtin_amdgcn_readlane(__float_as_int(x), 63));
}

__device__ __forceinline__ void load_chunk8(float4* p, float* p4, const float* pb,
                                            int t0, int Tb, int lane) {
  #pragma unroll
  for (int k = 0; k < 8; k++) {
    int t = t0 + k; t = (t < Tb) ? t : (Tb - 1);
    const float* row = pb + (size_t)t * SPAD;
    p[k] = *(const float4*)(row + (lane << 2));
    const float v = row[256];
    p4[k] = (lane == 63) ? v : 0.f;   // state 256 lives only in lane 63
  }
}

__global__ void k_ctc(const float* __restrict__ pext, const int* __restrict__ target,
                      const int* __restrict__ ilen, const int* __restrict__ tlen,
                      float* __restrict__ loss, int T, int L) {
  const int b = blockIdx.x;
  const int lane = threadIdx.x;          // 64 threads = 1 wave
  const int Tb = ilen[b];
  const int Lb = tlen[b];
  const int S = 2 * Lb + 1;
  const int* tg = target + b * L;

  // lane owns states 4l..4l+3 (lane 63 also 256). Skip flags (odd states only).
  const int s1 = 4 * lane + 1, s3 = 4 * lane + 3;
  float sk1 = 0.f, sk3 = 0.f;
  if (s1 >= 3 && s1 < S) sk1 = (tg[(s1 - 1) >> 1] != tg[(s1 - 3) >> 1]) ? 1.f : 0.f;
  if (s3 >= 3 && s3 < S) sk3 = (tg[(s3 - 1) >> 1] != tg[(s3 - 3) >> 1]) ? 1.f : 0.f;

  const float* pb = pext + (size_t)b * T * SPAD;
  const float4 p0 = *(const float4*)(pb + (lane << 2));
  float a0 = (lane == 0) ? p0.x : 0.f;   // alpha0[0]
  float a1 = (lane == 0) ? p0.y : 0.f;   // alpha0[1]
  float a2 = 0.f, a3 = 0.f, a4 = 0.f;
  float log2C = 0.f;                     // exact integer power-of-two scale accumulator

  float4 pA[8], pB[8]; float p4A[8], p4B[8];
  int t0 = 1, phase = 0;
  if (t0 < Tb) load_chunk8(pA, p4A, pb, t0, Tb, lane);

  #define CTC_STEP(PP, P4) {                          \
    const float pm3 = wave_shr1(a3);                  \
    const float n0v = (a0 + pm3) * (PP).x;            \
    const float n1v = (a1 + a0 + sk1 * pm3) * (PP).y; \
    const float n2v = (a2 + a1) * (PP).z;             \
    const float n3v = (a3 + a2 + sk3 * a1) * (PP).w;  \
    const float n4v = (a4 + a3) * (P4);               \
    a0 = n0v; a1 = n1v; a2 = n2v; a3 = n3v; a4 = n4v; }

  while (t0 < Tb) {
    const int tn = t0 + 8;
    if (phase == 0) {
      if (tn < Tb) load_chunk8(pB, p4B, pb, tn, Tb, lane);   // prefetch next chunk
      #pragma unroll
      for (int k = 0; k < 8; k++) { if (t0 + k < Tb) CTC_STEP(pA[k], p4A[k]); }
    } else {
      if (tn < Tb) load_chunk8(pA, p4A, pb, tn, Tb, lane);
      #pragma unroll
      for (int k = 0; k < 8; k++) { if (t0 + k < Tb) CTC_STEP(pB[k], p4B[k]); }
    }
    // renorm by exact power of two anchored at wave max (every 8 steps)
    float m = fmaxf(fmaxf(fmaxf(a0, a1), fmaxf(a2, a3)), a4);
    m = wave_max_nonneg(m);
    const int e = (int)((__float_as_uint(m) >> 23) & 255u) - 127;
    const float scale = __uint_as_float((uint32_t)(127 - e) << 23);   // 2^-e, exact
    a0 *= scale; a1 *= scale; a2 *= scale; a3 *= scale; a4 *= scale;
    log2C += (float)e;
    phase ^= 1; t0 = tn;
  }

  __shared__ float abuf[257];
  abuf[4 * lane + 0] = a0; abuf[4 * lane + 1] = a1;
  abuf[4 * lane + 2] = a2; abuf[4 * lane + 3] = a3;
  if (lane == 63) abuf[256] = a4;
  __syncthreads();
  if (lane == 0) {
    const float ssum = abuf[2 * Lb - 1] + abuf[2 * Lb];
    const float ll = (log2f(ssum) + log2C) * LN2;
    float nll = -ll;
    if (!(nll < 1e29f)) nll = 0.f;                 // zero_infinity (also catches inf/nan)
    loss[b] = nll / (float)(Lb > 0 ? Lb : 1);
  }
}

// ---------------- k4: mean over batch ----------------
__global__ void k_reduce(const float* __restrict__ loss, float* __restrict__ out, int B) {
  const int lane = threadIdx.x;
  float v = (lane < B) ? loss[lane] : 0.f;
  #pragma unroll
  for (int off = 32; off; off >>= 1) v += __shfl_xor(v, off, 64);
  if (lane == 0) out[0] = v / (float)B;
}

// ---------------------------------------------------------------------------
extern "C" void kernel_launch(void* const* d_in, const int* in_sizes, int n_in,
                              void* d_out, int out_size, void* d_ws, size_t ws_size,
                              hipStream_t stream) {
  const float* x      = (const float*)d_in[0];
  const float* W      = (const float*)d_in[1];
  const float* bias   = (const float*)d_in[2];
  const int*  target  = (const int*)d_in[3];
  const int*  ilen    = (const int*)d_in[4];
  const int*  tlen    = (const int*)d_in[5];

  const int B = in_sizes[4];
  const int V = in_sizes[2];
  const int D = in_sizes[1] / V;
  const int T = in_sizes[0] / (B * D);
  const int L = in_sizes[3] / B;
  const int M = B * T;

  char* ws = (char*)d_ws;
  const size_t xb_bytes = (size_t)M * D * 2;
  const size_t wt_bytes = (size_t)V * D * 2;
  const size_t pext_bytes = (size_t)M * SPAD * 4;
  uint16_t* xb = (uint16_t*)ws;
  uint16_t* Wt = (uint16_t*)(ws + xb_bytes);
  char* logits = ws + xb_bytes + wt_bytes;

  // prefer fp32 logits; fall back to bf16 logits if workspace is tight
  const size_t need_f32 = xb_bytes + wt_bytes + (size_t)M * V * 4 + 4096;
  const bool f32log = (ws_size >= need_f32);
  const size_t log_bytes = (size_t)M * V * (f32log ? 4 : 2);

  float* pext;
  size_t tail = xb_bytes + wt_bytes + log_bytes;
  if (pext_bytes <= xb_bytes + wt_bytes) {
    pext = (float*)ws;                 // overlay dead x_bf16/Wt region after GEMM
  } else {
    pext = (float*)(ws + tail); tail += pext_bytes;
  }
  float* lossb = (float*)(ws + tail);

  const long long nx = (long long)M * D;
  k_convert_x<<<(int)((nx / 8 + 255) / 256), 256, 0, stream>>>(x, xb, nx);
  k_transpose_w<<<dim3(V / 32, D / 32), dim3(32, 8), 0, stream>>>(W, Wt, D, V);
  if (f32log) {
    float* lg = (float*)logits;
    k_gemm<float><<<dim3(M / 128, V / 128), 256, 0, stream>>>(xb, Wt, bias, lg, M, V, D);
    k_softmax_gather<float><<<M / 4, 256, 0, stream>>>(lg, target, tlen, pext, T, V, L);
  } else {
    uint16_t* lg = (uint16_t*)logits;
    k_gemm<uint16_t><<<dim3(M / 128, V / 128), 256, 0, stream>>>(xb, Wt, bias, lg, M, V, D);
    k_softmax_gather<uint16_t><<<M / 4, 256, 0, stream>>>(lg, target, tlen, pext, T, V, L);
  }
  k_ctc<<<B, 64, 0, stream>>>(pext, target, ilen, tlen, lossb, T, L);
  k_reduce<<<1, 64, 0, stream>>>(lossb, (float*)d_out, B);
}

// Round 2
// 177.008 us; speedup vs baseline: 1.3901x; 1.3901x over previous
//
#include <hip/hip_runtime.h>
#include <cstdint>

// ---------------------------------------------------------------------------
// CTC loss pipeline: bf16 MFMA GEMM -> log_softmax+gather(exp) -> linear-domain
// scaled CTC forward -> mean reduce.
// ---------------------------------------------------------------------------

#define SPAD 260                      // padded extended-state row (257 -> 260, 16B-aligned rows)
#define PEXT_PAD_ROWS 32              // prefetch overrun pad (loaded, never consumed)
#define L2E 1.4426950408889634f
#define LN2 0.6931471805599453f

typedef short v8s __attribute__((ext_vector_type(8)));
typedef float v4f __attribute__((ext_vector_type(4)));

__device__ __forceinline__ uint32_t f2bf_bits(float f) {
  uint32_t u = __float_as_uint(f);
  return (u + 0x7FFFu + ((u >> 16) & 1u)) >> 16;   // RNE
}
__device__ __forceinline__ float bf2f(uint32_t h) { return __uint_as_float(h << 16); }

// ---------------- k0a: x fp32 -> bf16 ----------------
__global__ void k_convert_x(const float* __restrict__ x, uint16_t* __restrict__ xb, long long n) {
  long long i = ((long long)blockIdx.x * blockDim.x + threadIdx.x) * 8;
  if (i >= n) return;
  float4 a = *(const float4*)(x + i);
  float4 b = *(const float4*)(x + i + 4);
  uint4 o;
  o.x = f2bf_bits(a.x) | (f2bf_bits(a.y) << 16);
  o.y = f2bf_bits(a.z) | (f2bf_bits(a.w) << 16);
  o.z = f2bf_bits(b.x) | (f2bf_bits(b.y) << 16);
  o.w = f2bf_bits(b.z) | (f2bf_bits(b.w) << 16);
  *(uint4*)(xb + i) = o;
}

// ---------------- k0b: W[D,V] fp32 -> Wt[V,D] bf16 (transpose via LDS) ----------------
__global__ void k_transpose_w(const float* __restrict__ W, uint16_t* __restrict__ Wt, int D, int V) {
  __shared__ float tile[32][33];
  int n0 = blockIdx.x * 32, k0 = blockIdx.y * 32;
  int tx = threadIdx.x, ty = threadIdx.y;   // block (32,8)
  #pragma unroll
  for (int i = 0; i < 32; i += 8)
    tile[ty + i][tx] = W[(size_t)(k0 + ty + i) * V + n0 + tx];
  __syncthreads();
  #pragma unroll
  for (int i = 0; i < 32; i += 8)
    Wt[(size_t)(n0 + ty + i) * D + k0 + tx] = (uint16_t)f2bf_bits(tile[tx][ty + i]);
}

// ---------------- k1: bf16 GEMM (m97 structure), C = A*Wt^T + bias ----------------
template <typename CT>
__global__ __launch_bounds__(256) void k_gemm(const uint16_t* __restrict__ A,
                                              const uint16_t* __restrict__ Bt,
                                              const float* __restrict__ bias,
                                              CT* __restrict__ C, int M, int N, int K) {
  __shared__ uint16_t As[128 * 32];   // 8 KB, row r at ushort r*32
  __shared__ uint16_t Bs[128 * 32];
  const int tid = threadIdx.x, lane = tid & 63, wave = tid >> 6;
  const int m0 = blockIdx.x * 128, n0 = blockIdx.y * 128;
  const int wm = wave & 1, wn = wave >> 1;
  const int frow = lane & 15, kb = lane >> 4;
  const int lr = lane >> 2, kc = lane & 3;
  v4f acc[4][4] = {};

  for (int k0 = 0; k0 < K; k0 += 32) {
    __syncthreads();
    #pragma unroll
    for (int i = 0; i < 2; i++) {
      const int r = (wave * 2 + i) * 16 + lr;
      const uint16_t* ga = A + (size_t)(m0 + r) * K + k0 + kc * 8;
      const uint16_t* gb = Bt + (size_t)(n0 + r) * K + k0 + kc * 8;
      __builtin_amdgcn_global_load_lds(
          (const __attribute__((address_space(1))) void*)ga,
          (__attribute__((address_space(3))) void*)(As + (wave * 2 + i) * 512 + lane * 8), 16, 0, 0);
      __builtin_amdgcn_global_load_lds(
          (const __attribute__((address_space(1))) void*)gb,
          (__attribute__((address_space(3))) void*)(Bs + (wave * 2 + i) * 512 + lane * 8), 16, 0, 0);
    }
    __syncthreads();

    v8s af[4], bf[4];
    #pragma unroll
    for (int i = 0; i < 4; i++)
      af[i] = *(const v8s*)(As + (wm * 64 + i * 16 + frow) * 32 + kb * 8);
    #pragma unroll
    for (int j = 0; j < 4; j++)
      bf[j] = *(const v8s*)(Bs + (wn * 64 + j * 16 + frow) * 32 + kb * 8);
    #pragma unroll
    for (int i = 0; i < 4; i++)
      #pragma unroll
      for (int j = 0; j < 4; j++)
        acc[i][j] = __builtin_amdgcn_mfma_f32_16x16x32_bf16(af[i], bf[j], acc[i][j], 0, 0, 0);
  }

  const int crow = (lane >> 4) * 4, ccol = lane & 15;
  #pragma unroll
  for (int j = 0; j < 4; j++) {
    const int n = n0 + wn * 64 + j * 16 + ccol;
    const float bv = bias[n];
    #pragma unroll
    for (int i = 0; i < 4; i++) {
      const int mb = m0 + wm * 64 + i * 16 + crow;
      #pragma unroll
      for (int r2 = 0; r2 < 4; r2++) {
        float v = acc[i][j][r2] + bv;
        if constexpr (sizeof(CT) == 2) C[(size_t)(mb + r2) * N + n] = (CT)f2bf_bits(v);
        else                           C[(size_t)(mb + r2) * N + n] = v;
      }
    }
  }
}

// ---------------- k2: per-row logsumexp + gather ext-label probs (linear domain) ----------------
template <typename CT>
__global__ void k_softmax_gather(const CT* __restrict__ logits, const int* __restrict__ target,
                                 const int* __restrict__ tlen, float* __restrict__ pext,
                                 int T, int V, int L) {
  const int row = blockIdx.x * 4 + (threadIdx.x >> 6);   // one wave per row
  const int lane = threadIdx.x & 63;
  const CT* lrow = logits + (size_t)row * V;

  float xs[16];
  int cnt = 0;
  float mx = -INFINITY;
  for (int base = 0; base < V; base += 256) {
    const int idx = base + lane * 4;
    float4 v;
    if constexpr (sizeof(CT) == 2) {
      uint2 u = *(const uint2*)((const uint16_t*)lrow + idx);
      v.x = bf2f(u.x & 0xFFFFu); v.y = bf2f(u.x >> 16);
      v.z = bf2f(u.y & 0xFFFFu); v.w = bf2f(u.y >> 16);
    } else {
      v = *(const float4*)((const float*)lrow + idx);
    }
    xs[cnt] = v.x; xs[cnt + 1] = v.y; xs[cnt + 2] = v.z; xs[cnt + 3] = v.w; cnt += 4;
    mx = fmaxf(mx, fmaxf(fmaxf(v.x, v.y), fmaxf(v.z, v.w)));
  }
  #pragma unroll
  for (int off = 32; off; off >>= 1) mx = fmaxf(mx, __shfl_xor(mx, off, 64));
  float sum = 0.f;
  #pragma unroll
  for (int q = 0; q < 16; q++) { if (q < cnt) sum += exp2f((xs[q] - mx) * L2E); }
  #pragma unroll
  for (int off = 32; off; off >>= 1) sum += __shfl_xor(sum, off, 64);
  const float lse2 = mx * L2E + log2f(sum);

  const int bidx = row / T;
  const int Lb = tlen[bidx];
  const int S = 2 * Lb + 1;
  float* prow = pext + (size_t)row * SPAD;
  for (int s = lane; s < SPAD; s += 64) {
    float p = 0.f;
    if (s < S) {
      const int lbl = (s & 1) ? target[bidx * L + ((s - 1) >> 1)] : 0;
      float lg;
      if constexpr (sizeof(CT) == 2) lg = bf2f(((const uint16_t*)lrow)[lbl]);
      else                           lg = ((const float*)lrow)[lbl];
      p = exp2f(lg * L2E - lse2);
    }
    prow[s] = p;
  }
}

// ---------------- k3: scaled linear-domain CTC forward, 1 wave per batch ----------------
__device__ __forceinline__ float wave_shr1(float x) {   // lane l <- lane l-1, lane0 <- 0
  return __int_as_float(__builtin_amdgcn_update_dpp(0, __float_as_int(x), 0x138, 0xf, 0xf, true));
}
__device__ __forceinline__ float wave_max_nonneg(float x) {
  x = fmaxf(x, __int_as_float(__builtin_amdgcn_update_dpp(0, __float_as_int(x), 0x111, 0xf, 0xf, true)));
  x = fmaxf(x, __int_as_float(__builtin_amdgcn_update_dpp(0, __float_as_int(x), 0x112, 0xf, 0xf, true)));
  x = fmaxf(x, __int_as_float(__builtin_amdgcn_update_dpp(0, __float_as_int(x), 0x114, 0xf, 0xf, true)));
  x = fmaxf(x, __int_as_float(__builtin_amdgcn_update_dpp(0, __float_as_int(x), 0x118, 0xf, 0xf, true)));
  x = fmaxf(x, __int_as_float(__builtin_amdgcn_update_dpp(0, __float_as_int(x), 0x142, 0xf, 0xf, true)));
  x = fmaxf(x, __int_as_float(__builtin_amdgcn_update_dpp(0, __float_as_int(x), 0x143, 0xf, 0xf, true)));
  return __int_as_float(__builtin_amdgcn_readlane(__float_as_int(x), 63));
}

// 16-row chunk load: pure loads, no clamps, no selects, no guards.
// Rows beyond Tb hit the PEXT_PAD_ROWS pad (or the next batch's data) and are
// never consumed. row[256] is a wave-broadcast load (same addr all lanes).
__device__ __forceinline__ void load16(float4* __restrict__ p, float* __restrict__ p4,
                                       const float* __restrict__ pb, int t0, int lane) {
  #pragma unroll
  for (int k = 0; k < 16; k++) {
    const float* row = pb + (size_t)(t0 + k) * SPAD;
    p[k] = *(const float4*)(row + (lane << 2));
    p4[k] = row[256];
  }
}

__global__ __launch_bounds__(64, 1) void k_ctc(const float* __restrict__ pext,
                                               const int* __restrict__ target,
                                               const int* __restrict__ ilen,
                                               const int* __restrict__ tlen,
                                               float* __restrict__ loss, int T, int L) {
  const int b = blockIdx.x;
  const int lane = threadIdx.x;          // 64 threads = 1 wave
  const int Tb = ilen[b];
  const int Lb = tlen[b];
  const int S = 2 * Lb + 1;
  const int* tg = target + b * L;

  // lane owns states 4l..4l+3; state 256 (blank) is carried identically in ALL
  // lanes (broadcast p, broadcast update) and read back from lane 63.
  const int s1 = 4 * lane + 1, s3 = 4 * lane + 3;
  float sk1 = 0.f, sk3 = 0.f;
  if (s1 >= 3 && s1 < S) sk1 = (tg[(s1 - 1) >> 1] != tg[(s1 - 3) >> 1]) ? 1.f : 0.f;
  if (s3 >= 3 && s3 < S) sk3 = (tg[(s3 - 1) >> 1] != tg[(s3 - 3) >> 1]) ? 1.f : 0.f;

  const float* pb = pext + (size_t)b * T * SPAD;
  const float4 p0 = *(const float4*)(pb + (lane << 2));
  float a0 = (lane == 0) ? p0.x : 0.f;
  float a1 = (lane == 0) ? p0.y : 0.f;
  float a2 = 0.f, a3 = 0.f, a4 = 0.f;
  float log2C = 0.f;

  // state-256 update uses alpha[255] = a3 of lane 63, broadcast to all lanes
  #define CTC_STEP(PP, P4) {                                            \
    const float pm3 = wave_shr1(a3);                                    \
    const float a255 = __int_as_float(__builtin_amdgcn_readlane(__float_as_int(a3), 63)); \
    const float n0v = (a0 + pm3) * (PP).x;                              \
    const float n1v = (a1 + a0 + sk1 * pm3) * (PP).y;                   \
    const float n2v = (a2 + a1) * (PP).z;                               \
    const float n3v = (a3 + a2 + sk3 * a1) * (PP).w;                    \
    const float n4v = (a4 + a255) * (P4);                               \
    a0 = n0v; a1 = n1v; a2 = n2v; a3 = n3v; a4 = n4v; }

  #define RENORM {                                                      \
    float m = fmaxf(fmaxf(fmaxf(a0, a1), fmaxf(a2, a3)), a4);           \
    m = wave_max_nonneg(m);                                             \
    const int e = (int)((__float_as_uint(m) >> 23) & 255u) - 127;       \
    const float scale = __uint_as_float((uint32_t)(127 - e) << 23);     \
    a0 *= scale; a1 *= scale; a2 *= scale; a3 *= scale; a4 *= scale;    \
    log2C += (float)e; }

  float4 pA[16], pB[16];
  float p4A[16], p4B[16];
  int t0 = 1;
  load16(pA, p4A, pb, t0, lane);

  while (t0 < Tb) {
    // consume A, prefetch B
    load16(pB, p4B, pb, t0 + 16, lane);
    #pragma unroll
    for (int k = 0; k < 16; k++) {
      if (t0 + k < Tb) CTC_STEP(pA[k], p4A[k]);
      if ((k & 7) == 7) RENORM;
    }
    t0 += 16;
    if (t0 >= Tb) break;
    // consume B, prefetch A
    load16(pA, p4A, pb, t0 + 16, lane);
    #pragma unroll
    for (int k = 0; k < 16; k++) {
      if (t0 + k < Tb) CTC_STEP(pB[k], p4B[k]);
      if ((k & 7) == 7) RENORM;
    }
    t0 += 16;
  }

  __shared__ float abuf[257];
  abuf[4 * lane + 0] = a0; abuf[4 * lane + 1] = a1;
  abuf[4 * lane + 2] = a2; abuf[4 * lane + 3] = a3;
  if (lane == 63) abuf[256] = a4;
  __syncthreads();
  if (lane == 0) {
    const float ssum = abuf[2 * Lb - 1] + abuf[2 * Lb];
    const float ll = (log2f(ssum) + log2C) * LN2;
    float nll = -ll;
    if (!(nll < 1e29f)) nll = 0.f;                 // zero_infinity (also catches inf/nan)
    loss[b] = nll / (float)(Lb > 0 ? Lb : 1);
  }
}

// ---------------- k4: mean over batch ----------------
__global__ void k_reduce(const float* __restrict__ loss, float* __restrict__ out, int B) {
  const int lane = threadIdx.x;
  float v = (lane < B) ? loss[lane] : 0.f;
  #pragma unroll
  for (int off = 32; off; off >>= 1) v += __shfl_xor(v, off, 64);
  if (lane == 0) out[0] = v / (float)B;
}

// ---------------------------------------------------------------------------
extern "C" void kernel_launch(void* const* d_in, const int* in_sizes, int n_in,
                              void* d_out, int out_size, void* d_ws, size_t ws_size,
                              hipStream_t stream) {
  const float* x      = (const float*)d_in[0];
  const float* W      = (const float*)d_in[1];
  const float* bias   = (const float*)d_in[2];
  const int*  target  = (const int*)d_in[3];
  const int*  ilen    = (const int*)d_in[4];
  const int*  tlen    = (const int*)d_in[5];

  const int B = in_sizes[4];
  const int V = in_sizes[2];
  const int D = in_sizes[1] / V;
  const int T = in_sizes[0] / (B * D);
  const int L = in_sizes[3] / B;
  const int M = B * T;

  char* ws = (char*)d_ws;
  const size_t xb_bytes = (size_t)M * D * 2;
  const size_t wt_bytes = (size_t)V * D * 2;
  const size_t pext_bytes = (size_t)(M + PEXT_PAD_ROWS) * SPAD * 4;
  uint16_t* xb = (uint16_t*)ws;
  uint16_t* Wt = (uint16_t*)(ws + xb_bytes);
  char* logits = ws + xb_bytes + wt_bytes;

  const size_t need_f32 = xb_bytes + wt_bytes + (size_t)M * V * 4 + 4096;
  const bool f32log = (ws_size >= need_f32);
  const size_t log_bytes = (size_t)M * V * (f32log ? 4 : 2);

  float* pext;
  size_t tail = xb_bytes + wt_bytes + log_bytes;
  if (pext_bytes <= xb_bytes + wt_bytes) {
    pext = (float*)ws;                 // overlay dead x_bf16/Wt region after GEMM
  } else {
    pext = (float*)(ws + tail); tail += pext_bytes;
  }
  float* lossb = (float*)(ws + tail);

  const long long nx = (long long)M * D;
  k_convert_x<<<(int)((nx / 8 + 255) / 256), 256, 0, stream>>>(x, xb, nx);
  k_transpose_w<<<dim3(V / 32, D / 32), dim3(32, 8), 0, stream>>>(W, Wt, D, V);
  if (f32log) {
    float* lg = (float*)logits;
    k_gemm<float><<<dim3(M / 128, V / 128), 256, 0, stream>>>(xb, Wt, bias, lg, M, V, D);
    k_softmax_gather<float><<<M / 4, 256, 0, stream>>>(lg, target, tlen, pext, T, V, L);
  } else {
    uint16_t* lg = (uint16_t*)logits;
    k_gemm<uint16_t><<<dim3(M / 128, V / 128), 256, 0, stream>>>(xb, Wt, bias, lg, M, V, D);
    k_softmax_gather<uint16_t><<<M / 4, 256, 0, stream>>>(lg, target, tlen, pext, T, V, L);
  }
  k_ctc<<<B, 64, 0, stream>>>(pext, target, ilen, tlen, lossb, T, L);
  k_reduce<<<1, 64, 0, stream>>>(lossb, (float*)d_out, B);
}

// Round 3
// 169.917 us; speedup vs baseline: 1.4481x; 1.0417x over previous
//
#include <hip/hip_runtime.h>
#include <cstdint>

// ---------------------------------------------------------------------------
// CTC loss pipeline: prep(cvt+transpose+zero) -> bf16 MFMA GEMM (bf16 logits)
// -> log_softmax+gather(exp) -> 4-deep-pipelined linear-domain CTC forward
// (atomicAdd mean into d_out).
// ---------------------------------------------------------------------------

#define SPAD 260                      // padded extended-state row (257 -> 260)
#define PEXT_PAD_ROWS 64              // prefetch overrun pad (loaded, never consumed)
#define L2E 1.4426950408889634f
#define LN2 0.6931471805599453f

typedef short v8s __attribute__((ext_vector_type(8)));
typedef float v4f __attribute__((ext_vector_type(4)));

__device__ __forceinline__ uint32_t f2bf_bits(float f) {
  uint32_t u = __float_as_uint(f);
  return (u + 0x7FFFu + ((u >> 16) & 1u)) >> 16;   // RNE
}
__device__ __forceinline__ float bf2f(uint32_t h) { return __uint_as_float(h << 16); }

// ---------------- k_prep: x fp32->bf16, W transpose->bf16, zero d_out ----------------
__global__ void k_prep(const float* __restrict__ x, uint16_t* __restrict__ xb, long long n,
                       const float* __restrict__ W, uint16_t* __restrict__ Wt, int D, int V,
                       float* __restrict__ out, int nconv) {
  if (blockIdx.x == 0 && threadIdx.x == 0) out[0] = 0.f;   // zero the atomic target
  if ((int)blockIdx.x < nconv) {
    long long i = ((long long)blockIdx.x * blockDim.x + threadIdx.x) * 8;
    if (i >= n) return;
    float4 a = *(const float4*)(x + i);
    float4 b = *(const float4*)(x + i + 4);
    uint4 o;
    o.x = f2bf_bits(a.x) | (f2bf_bits(a.y) << 16);
    o.y = f2bf_bits(a.z) | (f2bf_bits(a.w) << 16);
    o.z = f2bf_bits(b.x) | (f2bf_bits(b.y) << 16);
    o.w = f2bf_bits(b.z) | (f2bf_bits(b.w) << 16);
    *(uint4*)(xb + i) = o;
  } else {
    __shared__ float tile[32][33];
    const int bid2 = blockIdx.x - nconv;
    const int n0 = (bid2 % (V / 32)) * 32, k0 = (bid2 / (V / 32)) * 32;
    const int tx = threadIdx.x & 31, ty = threadIdx.x >> 5;   // (32,8)
    #pragma unroll
    for (int i = 0; i < 32; i += 8)
      tile[ty + i][tx] = W[(size_t)(k0 + ty + i) * V + n0 + tx];
    __syncthreads();
    #pragma unroll
    for (int i = 0; i < 32; i += 8)
      Wt[(size_t)(n0 + ty + i) * D + k0 + tx] = (uint16_t)f2bf_bits(tile[tx][ty + i]);
  }
}

// ---------------- k1: bf16 GEMM (m97 structure), C = A*Wt^T + bias, bf16 out ----------------
__global__ __launch_bounds__(256) void k_gemm(const uint16_t* __restrict__ A,
                                              const uint16_t* __restrict__ Bt,
                                              const float* __restrict__ bias,
                                              uint16_t* __restrict__ C, int M, int N, int K) {
  __shared__ uint16_t As[128 * 32];   // 8 KB, row r at ushort r*32
  __shared__ uint16_t Bs[128 * 32];
  const int tid = threadIdx.x, lane = tid & 63, wave = tid >> 6;
  const int m0 = blockIdx.x * 128, n0 = blockIdx.y * 128;
  const int wm = wave & 1, wn = wave >> 1;
  const int frow = lane & 15, kb = lane >> 4;
  const int lr = lane >> 2, kc = lane & 3;
  v4f acc[4][4] = {};

  for (int k0 = 0; k0 < K; k0 += 32) {
    __syncthreads();
    #pragma unroll
    for (int i = 0; i < 2; i++) {
      const int r = (wave * 2 + i) * 16 + lr;
      const uint16_t* ga = A + (size_t)(m0 + r) * K + k0 + kc * 8;
      const uint16_t* gb = Bt + (size_t)(n0 + r) * K + k0 + kc * 8;
      __builtin_amdgcn_global_load_lds(
          (const __attribute__((address_space(1))) void*)ga,
          (__attribute__((address_space(3))) void*)(As + (wave * 2 + i) * 512 + lane * 8), 16, 0, 0);
      __builtin_amdgcn_global_load_lds(
          (const __attribute__((address_space(1))) void*)gb,
          (__attribute__((address_space(3))) void*)(Bs + (wave * 2 + i) * 512 + lane * 8), 16, 0, 0);
    }
    __syncthreads();

    v8s af[4], bf[4];
    #pragma unroll
    for (int i = 0; i < 4; i++)
      af[i] = *(const v8s*)(As + (wm * 64 + i * 16 + frow) * 32 + kb * 8);
    #pragma unroll
    for (int j = 0; j < 4; j++)
      bf[j] = *(const v8s*)(Bs + (wn * 64 + j * 16 + frow) * 32 + kb * 8);
    #pragma unroll
    for (int i = 0; i < 4; i++)
      #pragma unroll
      for (int j = 0; j < 4; j++)
        acc[i][j] = __builtin_amdgcn_mfma_f32_16x16x32_bf16(af[i], bf[j], acc[i][j], 0, 0, 0);
  }

  const int crow = (lane >> 4) * 4, ccol = lane & 15;
  #pragma unroll
  for (int j = 0; j < 4; j++) {
    const int n = n0 + wn * 64 + j * 16 + ccol;
    const float bv = bias[n];
    #pragma unroll
    for (int i = 0; i < 4; i++) {
      const int mb = m0 + wm * 64 + i * 16 + crow;
      #pragma unroll
      for (int r2 = 0; r2 < 4; r2++)
        C[(size_t)(mb + r2) * N + n] = (uint16_t)f2bf_bits(acc[i][j][r2] + bv);
    }
  }
}

// ---------------- k2: per-row logsumexp + gather ext-label probs (linear domain) ----------------
__global__ void k_softmax_gather(const uint16_t* __restrict__ logits, const int* __restrict__ target,
                                 const int* __restrict__ tlen, float* __restrict__ pext,
                                 int T, int V, int L) {
  const int row = blockIdx.x * 4 + (threadIdx.x >> 6);   // one wave per row
  const int lane = threadIdx.x & 63;
  const uint16_t* lrow = logits + (size_t)row * V;

  float xs[16];
  int cnt = 0;
  float mx = -INFINITY;
  for (int base = 0; base < V; base += 256) {
    const int idx = base + lane * 4;
    uint2 u = *(const uint2*)(lrow + idx);
    float4 v;
    v.x = bf2f(u.x & 0xFFFFu); v.y = bf2f(u.x >> 16);
    v.z = bf2f(u.y & 0xFFFFu); v.w = bf2f(u.y >> 16);
    xs[cnt] = v.x; xs[cnt + 1] = v.y; xs[cnt + 2] = v.z; xs[cnt + 3] = v.w; cnt += 4;
    mx = fmaxf(mx, fmaxf(fmaxf(v.x, v.y), fmaxf(v.z, v.w)));
  }
  #pragma unroll
  for (int off = 32; off; off >>= 1) mx = fmaxf(mx, __shfl_xor(mx, off, 64));
  float sum = 0.f;
  #pragma unroll
  for (int q = 0; q < 16; q++) { if (q < cnt) sum += exp2f((xs[q] - mx) * L2E); }
  #pragma unroll
  for (int off = 32; off; off >>= 1) sum += __shfl_xor(sum, off, 64);
  const float lse2 = mx * L2E + log2f(sum);

  const int bidx = row / T;
  const int Lb = tlen[bidx];
  const int S = 2 * Lb + 1;
  float* prow = pext + (size_t)row * SPAD;
  for (int s = lane; s < SPAD; s += 64) {
    float p = 0.f;
    if (s < S) {
      const int lbl = (s & 1) ? target[bidx * L + ((s - 1) >> 1)] : 0;
      p = exp2f(bf2f(lrow[lbl]) * L2E - lse2);
    }
    prow[s] = p;
  }
}

// ---------------- k3: scaled linear-domain CTC forward, 1 wave per batch ----------------
__device__ __forceinline__ float wave_shr1(float x) {   // lane l <- lane l-1, lane0 <- 0
  return __int_as_float(__builtin_amdgcn_update_dpp(0, __float_as_int(x), 0x138, 0xf, 0xf, true));
}
__device__ __forceinline__ float wave_max_nonneg(float x) {
  x = fmaxf(x, __int_as_float(__builtin_amdgcn_update_dpp(0, __float_as_int(x), 0x111, 0xf, 0xf, true)));
  x = fmaxf(x, __int_as_float(__builtin_amdgcn_update_dpp(0, __float_as_int(x), 0x112, 0xf, 0xf, true)));
  x = fmaxf(x, __int_as_float(__builtin_amdgcn_update_dpp(0, __float_as_int(x), 0x114, 0xf, 0xf, true)));
  x = fmaxf(x, __int_as_float(__builtin_amdgcn_update_dpp(0, __float_as_int(x), 0x118, 0xf, 0xf, true)));
  x = fmaxf(x, __int_as_float(__builtin_amdgcn_update_dpp(0, __float_as_int(x), 0x142, 0xf, 0xf, true)));
  x = fmaxf(x, __int_as_float(__builtin_amdgcn_update_dpp(0, __float_as_int(x), 0x143, 0xf, 0xf, true)));
  return __int_as_float(__builtin_amdgcn_readlane(__float_as_int(x), 63));
}

// 8-row chunk load: pure loads — no clamps, no selects, no guards.
__device__ __forceinline__ void load8(float4* __restrict__ p, float* __restrict__ p4,
                                      const float* __restrict__ pb, int t0, int lane) {
  #pragma unroll
  for (int k = 0; k < 8; k++) {
    const float* row = pb + (size_t)(t0 + k) * SPAD;
    p[k] = *(const float4*)(row + (lane << 2));
    p4[k] = row[256];               // wave-broadcast load
  }
}

__global__ __launch_bounds__(64, 1) void k_ctc(const float* __restrict__ pext,
                                               const int* __restrict__ target,
                                               const int* __restrict__ ilen,
                                               const int* __restrict__ tlen,
                                               float* __restrict__ out, int T, int L) {
  const int b = blockIdx.x;
  const int lane = threadIdx.x;          // 64 threads = 1 wave
  const int B = gridDim.x;
  const int Tb = ilen[b];
  const int Lb = tlen[b];
  const int S = 2 * Lb + 1;
  const int* tg = target + b * L;

  // lane owns states 4l..4l+3; state 256 carried identically in all lanes.
  const int s1 = 4 * lane + 1, s3 = 4 * lane + 3;
  float sk1 = 0.f, sk3 = 0.f;
  if (s1 >= 3 && s1 < S) sk1 = (tg[(s1 - 1) >> 1] != tg[(s1 - 3) >> 1]) ? 1.f : 0.f;
  if (s3 >= 3 && s3 < S) sk3 = (tg[(s3 - 1) >> 1] != tg[(s3 - 3) >> 1]) ? 1.f : 0.f;

  const float* pb = pext + (size_t)b * T * SPAD;
  const float4 p0 = *(const float4*)(pb + (lane << 2));
  float a0 = (lane == 0) ? p0.x : 0.f;
  float a1 = (lane == 0) ? p0.y : 0.f;
  float a2 = 0.f, a3 = 0.f, a4 = 0.f;
  float log2C = 0.f;

  #define CTC_STEP(PP, P4) {                                            \
    const float pm3 = wave_shr1(a3);                                    \
    const float a255 = __int_as_float(__builtin_amdgcn_readlane(__float_as_int(a3), 63)); \
    const float n0v = (a0 + pm3) * (PP).x;                              \
    const float n1v = (a1 + a0 + sk1 * pm3) * (PP).y;                   \
    const float n2v = (a2 + a1) * (PP).z;                               \
    const float n3v = (a3 + a2 + sk3 * a1) * (PP).w;                    \
    const float n4v = (a4 + a255) * (P4);                               \
    a0 = n0v; a1 = n1v; a2 = n2v; a3 = n3v; a4 = n4v; }

  #define RENORM {                                                      \
    float m = fmaxf(fmaxf(fmaxf(a0, a1), fmaxf(a2, a3)), a4);           \
    m = wave_max_nonneg(m);                                             \
    const int e = (int)((__float_as_uint(m) >> 23) & 255u) - 127;       \
    const float scale = __uint_as_float((uint32_t)(127 - e) << 23);     \
    a0 *= scale; a1 *= scale; a2 *= scale; a3 *= scale; a4 *= scale;    \
    log2C += (float)e; }

  // 4-stage software pipeline, 8-row chunks, prefetch distance = 3 chunks.
  float4 Pa[8], Pb_[8], Pc[8], Pd[8];
  float Qa[8], Qb[8], Qc[8], Qd[8];
  int t0 = 1;
  bool done = false;
  load8(Pa, Qa, pb, t0, lane);
  load8(Pb_, Qb, pb, t0 + 8, lane);
  load8(Pc, Qc, pb, t0 + 16, lane);

  #define PHASE(LP, LQ, CP, CQ) {                                       \
    if (t0 + 8 <= Tb) {                                                 \
      load8(LP, LQ, pb, t0 + 24, lane);                                 \
      _Pragma("unroll")                                                 \
      for (int k = 0; k < 8; k++) CTC_STEP(CP[k], CQ[k]);               \
      RENORM; t0 += 8;                                                  \
    } else {                                                            \
      _Pragma("unroll")                                                 \
      for (int k = 0; k < 8; k++) { if (t0 + k < Tb) CTC_STEP(CP[k], CQ[k]); } \
      RENORM; done = true;                                              \
    } }

  while (!done) {
    PHASE(Pd, Qd, Pa, Qa); if (done) break;
    PHASE(Pa, Qa, Pb_, Qb); if (done) break;
    PHASE(Pb_, Qb, Pc, Qc); if (done) break;
    PHASE(Pc, Qc, Pd, Qd);
  }

  __shared__ float abuf[257];
  abuf[4 * lane + 0] = a0; abuf[4 * lane + 1] = a1;
  abuf[4 * lane + 2] = a2; abuf[4 * lane + 3] = a3;
  if (lane == 63) abuf[256] = a4;
  __syncthreads();
  if (lane == 0) {
    const float ssum = abuf[2 * Lb - 1] + abuf[2 * Lb];
    const float ll = (log2f(ssum) + log2C) * LN2;
    float nll = -ll;
    if (!(nll < 1e29f)) nll = 0.f;                 // zero_infinity (also catches inf/nan)
    atomicAdd(out, nll / ((float)(Lb > 0 ? Lb : 1) * (float)B));
  }
}

// ---------------------------------------------------------------------------
extern "C" void kernel_launch(void* const* d_in, const int* in_sizes, int n_in,
                              void* d_out, int out_size, void* d_ws, size_t ws_size,
                              hipStream_t stream) {
  const float* x      = (const float*)d_in[0];
  const float* W      = (const float*)d_in[1];
  const float* bias   = (const float*)d_in[2];
  const int*  target  = (const int*)d_in[3];
  const int*  ilen    = (const int*)d_in[4];
  const int*  tlen    = (const int*)d_in[5];

  const int B = in_sizes[4];
  const int V = in_sizes[2];
  const int D = in_sizes[1] / V;
  const int T = in_sizes[0] / (B * D);
  const int L = in_sizes[3] / B;
  const int M = B * T;

  char* ws = (char*)d_ws;
  const size_t xb_bytes = (size_t)M * D * 2;
  const size_t wt_bytes = (size_t)V * D * 2;
  const size_t pext_bytes = (size_t)(M + PEXT_PAD_ROWS) * SPAD * 4;
  uint16_t* xb = (uint16_t*)ws;
  uint16_t* Wt = (uint16_t*)(ws + xb_bytes);
  uint16_t* logits = (uint16_t*)(ws + xb_bytes + wt_bytes);
  const size_t log_bytes = (size_t)M * V * 2;

  float* pext;
  if (pext_bytes <= xb_bytes + wt_bytes) {
    pext = (float*)ws;                 // overlay dead xb/Wt region after GEMM
  } else {
    pext = (float*)(ws + xb_bytes + wt_bytes + log_bytes);
  }

  const long long nx = (long long)M * D;
  const int nconv = (int)((nx / 8 + 255) / 256);
  const int ntrans = (V / 32) * (D / 32);
  k_prep<<<nconv + ntrans, 256, 0, stream>>>(x, xb, nx, W, Wt, D, V, (float*)d_out, nconv);
  k_gemm<<<dim3(M / 128, V / 128), 256, 0, stream>>>(xb, Wt, bias, logits, M, V, D);
  k_softmax_gather<<<M / 4, 256, 0, stream>>>(logits, target, tlen, pext, T, V, L);
  k_ctc<<<B, 64, 0, stream>>>(pext, target, ilen, tlen, (float*)d_out, T, L);
}